// Round 10
// baseline (566.611 us; speedup 1.0000x reference)
//
#include <hip/hip_runtime.h>
#include <hip/hip_bf16.h>
#include <hip/hip_fp16.h>
#include <stdint.h>

#define N_NODES 100000
#define N_EDGES 1600000
#define ET (N_EDGES + N_NODES)   // edges + self-loops
#define HID 128
#define C2 40
#define F2 80
#define NEG 0.2f
#define BN_EPS 1e-5f
#define NBUCK 391                // ceil(100000/256) scan blocks
#define CH2 256                  // per-NODE LDS edge cache (max deg ~45 << 256)

typedef __hip_bfloat16 bf16;
typedef __attribute__((ext_vector_type(8))) short s8v;          // 8 bf16 MFMA A/B frag
typedef __attribute__((ext_vector_type(4))) float f4v;          // MFMA C/D frag
typedef __attribute__((ext_vector_type(4))) unsigned int u4v;
typedef __attribute__((ext_vector_type(2))) unsigned int u2v;

__device__ __forceinline__ float b2f(bf16 v){ return __bfloat162float(v); }
__device__ __forceinline__ float rdf(const void* p, size_t i, int isb){
    return isb ? b2f(((const bf16*)p)[i]) : ((const float*)p)[i];
}
__device__ __forceinline__ unsigned short f2bb(float v){
    bf16 h = __float2bfloat16(v);
    return *(unsigned short*)&h;
}
__device__ __forceinline__ uint32_t pack2(float a, float b){
    return (uint32_t)f2bb(a) | ((uint32_t)f2bb(b) << 16);
}
__device__ __forceinline__ uint32_t packh2(float a, float b){
    return (uint32_t)__half_as_ushort(__float2half(a))
         | ((uint32_t)__half_as_ushort(__float2half(b)) << 16);
}
__device__ __forceinline__ float lo16(uint32_t u){ return __uint_as_float(u << 16); }
__device__ __forceinline__ float hi16(uint32_t u){ return __uint_as_float(u & 0xFFFF0000u); }
__device__ __forceinline__ float hcvt(uint32_t w, int sh){
    return __half2float(__ushort_as_half((unsigned short)((w >> sh) & 0xFFFFu)));
}

// ---------------- init: dtype flag + zero stats + zero deg ------------------
__global__ __launch_bounds__(256) void k_init(
    const uint32_t* __restrict__ w1bits, int* __restrict__ flag,
    float* __restrict__ stats, int* __restrict__ deg)
{
    __shared__ int cnt;
    int t = threadIdx.x;
    int dg = blockIdx.x*256 + t;
    if (dg < N_NODES) deg[dg] = 0;
    if (blockIdx.x == 0){
        if (t == 0) cnt = 0;
        __syncthreads();
        uint32_t b = w1bits[t];
        float lo = __uint_as_float((b & 0xFFFFu) << 16);
        float a = fabsf(lo);
        if (a > 1e-8f && a < 1.0f) atomicAdd(&cnt, 1);
        stats[t] = 0.f;
        __syncthreads();
        if (t == 0) *flag = (cnt >= 192) ? 1 : 0;
    }
}

// ---------------- GEMM1 (MFMA): h1 = x @ W1, + fused att1 dots --------------
__global__ __launch_bounds__(256) void k_gemm1(
    const void* __restrict__ x, const void* __restrict__ W1,
    const void* __restrict__ attS, const void* __restrict__ attD,
    const int* __restrict__ flag, unsigned short* __restrict__ h1,
    float* __restrict__ aS, float* __restrict__ aD)
{
    __shared__ __attribute__((aligned(16))) unsigned short wT[128*132]; // 33.8 KB
    const int isb = *flag;
    const int tid = threadIdx.x;
    if (isb) {
        const unsigned short* w = (const unsigned short*)W1;
        for (int idx = tid; idx < 128*128; idx += 256){
            int k = idx >> 7, n = idx & 127;
            wT[n*132 + k] = w[idx];
        }
    } else {
        const float* w = (const float*)W1;
        for (int idx = tid; idx < 128*128; idx += 256){
            int k = idx >> 7, n = idx & 127;
            wT[n*132 + k] = f2bb(w[idx]);
        }
    }
    __syncthreads();

    const int w4 = tid >> 6, lane = tid & 63, quad = lane >> 4, l16 = lane & 15;
    const int rowbase = blockIdx.x*32 + (w4 >> 1)*16;   // 3125*32 = 100000 exact
    const int colbase = (w4 & 1)*64;
    const int head = w4 & 1;

    s8v bfr[4][4];
    float asv[4], adv[4];
    #pragma unroll
    for (int ct = 0; ct < 4; ct++){
        int n = colbase + ct*16 + l16;
        asv[ct] = rdf(attS, n, isb);
        adv[ct] = rdf(attD, n, isb);
        #pragma unroll
        for (int s = 0; s < 4; s++){
            int k0 = s*32 + quad*8;
            const unsigned short* p = &wT[n*132 + k0];
            u2v a = *(const u2v*)p, b = *(const u2v*)(p+4);
            union { u4v u; s8v s; } cv; cv.u = (u4v){a[0],a[1],b[0],b[1]};
            bfr[ct][s] = cv.s;
        }
    }

    f4v acc[4];
    #pragma unroll
    for (int ct = 0; ct < 4; ct++) acc[ct] = (f4v){0.f,0.f,0.f,0.f};

    const int m = rowbase + l16;
    #pragma unroll
    for (int s = 0; s < 4; s++){
        int k0 = s*32 + quad*8;
        s8v af;
        if (isb){
            union { u4v u; s8v s; } cv;
            cv.u = *(const u4v*)((const unsigned short*)x + (size_t)m*128 + k0);
            af = cv.s;
        } else {
            const float* xp = (const float*)x + (size_t)m*128 + k0;
            f4v f0 = *(const f4v*)xp, f1 = *(const f4v*)(xp+4);
            union { u4v u; s8v s; } cv;
            cv.u = (u4v){pack2(f0[0],f0[1]), pack2(f0[2],f0[3]),
                         pack2(f1[0],f1[1]), pack2(f1[2],f1[3])};
            af = cv.s;
        }
        #pragma unroll
        for (int ct = 0; ct < 4; ct++)
            acc[ct] = __builtin_amdgcn_mfma_f32_16x16x32_bf16(af, bfr[ct][s], acc[ct], 0,0,0);
    }

    // C/D: col = lane&15, row = quad*4 + reg
    #pragma unroll
    for (int ct = 0; ct < 4; ct++){
        int col = colbase + ct*16 + l16;
        #pragma unroll
        for (int r = 0; r < 4; r++){
            int row = rowbase + quad*4 + r;
            h1[(size_t)row*128 + col] = f2bb(acc[ct][r]);
        }
    }

    // fused att1: per row, reduce acc*att over wave's 64 cols (one head).
    #pragma unroll
    for (int r = 0; r < 4; r++){
        float vs = 0.f, vd = 0.f;
        #pragma unroll
        for (int ct = 0; ct < 4; ct++){ vs += acc[ct][r]*asv[ct]; vd += acc[ct][r]*adv[ct]; }
        #pragma unroll
        for (int o = 1; o < 16; o <<= 1){
            vs += __shfl_xor(vs, o, 64);
            vd += __shfl_xor(vd, o, 64);
        }
        if (l16 == 0){
            int row = rowbase + quad*4 + r;
            aS[row*2 + head] = vs;
            aD[row*2 + head] = vd;
        }
    }
}

// ---------------- CSR 1: degree histogram (dense, low-contention) -----------
__global__ __launch_bounds__(256) void k_hist(
    const int* __restrict__ esrc, const int* __restrict__ edst,
    int* __restrict__ deg)
{
    for (int e = blockIdx.x*256 + threadIdx.x; e < ET; e += 1700*256){
        int d = (e < N_EDGES) ? edst[e] : e - N_EDGES;
        atomicAdd(&deg[d], 1);
    }
}

// ---------------- CSR 2a: per-block inclusive scan of deg -------------------
__global__ __launch_bounds__(256) void k_scan1(
    const int* __restrict__ deg, int* __restrict__ cur, int* __restrict__ bsum)
{
    __shared__ int sc[256];
    const int b = blockIdx.x, t = threadIdx.x;
    int dg = b*256 + t;
    int v = (dg < N_NODES) ? deg[dg] : 0;
    sc[t] = v;
    __syncthreads();
    for (int off = 1; off < 256; off <<= 1){
        int u = (t >= off) ? sc[t - off] : 0;
        __syncthreads();
        sc[t] += u;
        __syncthreads();
    }
    if (dg < N_NODES) cur[dg] = sc[t];       // local inclusive
    if (t == 255) bsum[b] = sc[255];
}

// ---------------- CSR 2b: scan of 391 block totals (1 block) ----------------
__global__ __launch_bounds__(512) void k_scan2(
    const int* __restrict__ bsum, int* __restrict__ bsumx)
{
    __shared__ int sc[512];
    const int t = threadIdx.x;
    int v = (t < NBUCK) ? bsum[t] : 0;
    sc[t] = v;
    __syncthreads();
    for (int off = 1; off < 512; off <<= 1){
        int u = (t >= off) ? sc[t - off] : 0;
        __syncthreads();
        sc[t] += u;
        __syncthreads();
    }
    if (t < NBUCK) bsumx[t] = sc[t] - v;     // exclusive
}

// ---------------- CSR 2c: add block base; cur=end ptr, curw=start ptr -------
__global__ __launch_bounds__(256) void k_scan3(
    const int* __restrict__ deg, const int* __restrict__ bsumx,
    int* __restrict__ cur, int* __restrict__ curw)
{
    int dg = blockIdx.x*256 + threadIdx.x;
    if (dg < N_NODES){
        int e = cur[dg] + bsumx[blockIdx.x];
        cur[dg]  = e;                        // end pointer (agg convention)
        curw[dg] = e - deg[dg];              // running write ptr for scatter
    }
}

// ---------------- CSR 3: scatter src into dense eidx ------------------------
// Order within a node's list is arbitrary (sum is order-independent).
__global__ __launch_bounds__(256) void k_scatter(
    const int* __restrict__ esrc, const int* __restrict__ edst,
    int* __restrict__ curw, int* __restrict__ eidx)
{
    for (int e = blockIdx.x*256 + threadIdx.x; e < ET; e += 1700*256){
        int s, d;
        if (e < N_EDGES){ s = esrc[e]; d = edst[e]; } else { s = d = e - N_EDGES; }
        int p = atomicAdd(&curw[d], 1);
        eidx[p] = s;
    }
}

// ---------------- layer-1 agg: 2 nodes/wave, 16 lanes/edge x dwordx4 --------
// (R3 form — best measured: 67 us.) Each half-wave (32 lanes) owns one node.
// c=ll&15 owns bytes 16c..16c+15 of edge-group g=ll>>4; 8 edges/iter with 4
// dwordx4 in flight. Phase 1 caches exp-weights in LDS with 32-lane
// parallelism; den reduce shared by both nodes; fold = ONE xor(16).
__global__ __launch_bounds__(256) void k_agg1(
    const int* __restrict__ cur, const int* __restrict__ deg,
    const int* __restrict__ eidx, const float* __restrict__ aS,
    const float* __restrict__ aD, const uint32_t* __restrict__ h1u,
    uint32_t* __restrict__ out1u)
{
    __shared__ uint2 lse[4][2][CH2 + 4];   // 16.6 KB
    const int wv = threadIdx.x >> 6;
    const int l = threadIdx.x & 63;
    const int half = l >> 5, ll = l & 31;
    const int d = blockIdx.x*8 + wv*2 + half;   // 12500*8 = 100000 exact
    const int c = ll & 15;               // feature slot within edge
    const int g = ll >> 4;               // edge group 0..1
    const uint32_t c16 = (uint32_t)(c*16);
    int end   = cur[d];
    int start = end - deg[d];
    float2 ad = *(const float2*)(aD + d*2);
    const int sh = (c >= 8) ? 16 : 0;    // cols 8c..8c+7: head1 iff 8c >= 64
    float den0 = 0.f, den1 = 0.f;
    float acc[8];
    #pragma unroll
    for (int k = 0; k < 8; k++) acc[k] = 0.f;
    const char* hb = (const char*)h1u;

#define G1(P, W) { u4v Gx = *(const u4v*)(hb + ((P).x + c16)); \
    float Wf = (W); \
    acc[0] += Wf*lo16(Gx[0]); acc[1] += Wf*hi16(Gx[0]); \
    acc[2] += Wf*lo16(Gx[1]); acc[3] += Wf*hi16(Gx[1]); \
    acc[4] += Wf*lo16(Gx[2]); acc[5] += Wf*hi16(Gx[2]); \
    acc[6] += Wf*lo16(Gx[3]); acc[7] += Wf*hi16(Gx[3]); }

    for (int c0 = start; c0 < end; c0 += CH2){
        int c1 = (c0 + CH2 < end) ? c0 + CH2 : end;
        int n = c1 - c0;
        // phase 1: half's 32 lanes parallel over this node's edges
        for (int j = c0 + ll; j < c1; j += 32){
            int s = eidx[j];
            float2 as = *(const float2*)((const char*)aS + ((uint32_t)s*8u));
            float al0 = as.x + ad.x, al1 = as.y + ad.y;
            al0 = al0 > 0.f ? al0 : NEG*al0;
            al1 = al1 > 0.f ? al1 : NEG*al1;
            float e0 = __expf(al0), e1 = __expf(al1);
            lse[wv][half][j - c0] = make_uint2((uint32_t)s << 8, packh2(e0, e1));
            den0 += e0; den1 += e1;
        }
        int nn = (n + 1) & ~1;
        if (ll < nn - n) lse[wv][half][n + ll] = make_uint2(0u, 0u);
        // same-wave LDS RAW: in-order per wave, no block barrier needed
        int i = 0;
        for (; i + 8 <= nn; i += 8){     // 4 rounds of 2 edges in flight
            uint2 pa = lse[wv][half][i + g];
            uint2 pb = lse[wv][half][i + 2 + g];
            uint2 pc = lse[wv][half][i + 4 + g];
            uint2 pd = lse[wv][half][i + 6 + g];
            G1(pa, hcvt(pa.y, sh));
            G1(pb, hcvt(pb.y, sh));
            G1(pc, hcvt(pc.y, sh));
            G1(pd, hcvt(pd.y, sh));
        }
        for (; i < nn; i += 2){
            uint2 pa = lse[wv][half][i + g];
            G1(pa, hcvt(pa.y, sh));
        }
    }
#undef G1
    // den reduce within each half (both nodes share the 5 rounds)
    #pragma unroll
    for (int o = 1; o < 32; o <<= 1){
        den0 += __shfl_xor(den0, o, 64);
        den1 += __shfl_xor(den1, o, 64);
    }
    // fold the 2 edge-groups of each half
    #pragma unroll
    for (int k = 0; k < 8; k++)
        acc[k] += __shfl_xor(acc[k], 16, 64);
    float r = 1.f / fmaxf((c < 8) ? den0 : den1, 1e-20f);
    if (ll < 16){
        u4v o;
        #pragma unroll
        for (int q = 0; q < 4; q++) o[q] = pack2(acc[2*q]*r, acc[2*q+1]*r);
        *(u4v*)(out1u + (size_t)d*64 + 4*c) = o;
    }
}

// ---------------- BatchNorm stats: per-block LDS reduce, then 1 atomic ------
__global__ __launch_bounds__(256) void k_bnstats(
    const uint32_t* __restrict__ out1u, float* __restrict__ stats)
{
    __shared__ float red[4][64][4];      // wave x feat-pair x {s0,s1,q0,q1} = 4 KB
    int fp = threadIdx.x & 63;
    int wv = threadIdx.x >> 6;
    float s0 = 0.f, q0 = 0.f, s1 = 0.f, q1 = 0.f;
    for (int r = blockIdx.x*4 + wv; r < N_NODES; r += 512){
        uint32_t u = out1u[(size_t)r*64 + fp];
        float f0 = lo16(u), f1 = hi16(u);
        s0 += f0; q0 += f0*f0; s1 += f1; q1 += f1*f1;
    }
    red[wv][fp][0] = s0; red[wv][fp][1] = s1;
    red[wv][fp][2] = q0; red[wv][fp][3] = q1;
    __syncthreads();
    if (threadIdx.x < 64){
        int l = threadIdx.x;
        float a0=0.f, a1=0.f, b0=0.f, b1=0.f;
        #pragma unroll
        for (int w = 0; w < 4; w++){
            a0 += red[w][l][0]; a1 += red[w][l][1];
            b0 += red[w][l][2]; b1 += red[w][l][3];
        }
        unsafeAtomicAdd(&stats[2*l],       a0);
        unsafeAtomicAdd(&stats[2*l+1],     a1);
        unsafeAtomicAdd(&stats[128+2*l],   b0);
        unsafeAtomicAdd(&stats[128+2*l+1], b1);
    }
}

// ---------------- GEMM2 (MFMA): h2 = BN(out1) @ W2, + fused att2, BN-fin ----
__global__ __launch_bounds__(256) void k_gemm2(
    const unsigned short* __restrict__ out1b, const float* __restrict__ stats,
    const void* __restrict__ gamma, const void* __restrict__ beta,
    const void* __restrict__ W2, const void* __restrict__ attS,
    const void* __restrict__ attD, const int* __restrict__ flag,
    unsigned short* __restrict__ h2, float* __restrict__ aS, float* __restrict__ aD)
{
    __shared__ __attribute__((aligned(16))) unsigned short wT[80*132]; // 21.1 KB
    __shared__ float scl[128], shl[128];
    const int isb = *flag;
    const int tid = threadIdx.x;
    for (int idx = tid; idx < 128*80; idx += 256){
        int k = idx / 80, n = idx - k*80;
        wT[n*132 + k] = isb ? ((const unsigned short*)W2)[idx]
                            : f2bb(((const float*)W2)[idx]);
    }
    if (tid < 128){   // inline BN finalize
        float mean = stats[tid] * (1.f / N_NODES);
        float var = fmaxf(stats[128+tid] * (1.f / N_NODES) - mean*mean, 0.f);
        float rs = rsqrtf(var + BN_EPS);
        float sc = rdf(gamma, tid, isb) * rs;
        scl[tid] = sc;
        shl[tid] = rdf(beta, tid, isb) - mean*sc;
    }
    __syncthreads();

    const int w4 = tid >> 6, lane = tid & 63, quad = lane >> 4, l16 = lane & 15;
    const int rowbase = blockIdx.x*64 + w4*16;

    s8v bfr[5][4];
    float asv[5], adv[5];
    #pragma unroll
    for (int ct = 0; ct < 5; ct++){
        int n = ct*16 + l16;
        asv[ct] = rdf(attS, n, isb);
        adv[ct] = rdf(attD, n, isb);
        #pragma unroll
        for (int s = 0; s < 4; s++){
            int k0 = s*32 + quad*8;
            const unsigned short* p = &wT[n*132 + k0];
            u2v a = *(const u2v*)p, b = *(const u2v*)(p+4);
            union { u4v u; s8v s; } cv; cv.u = (u4v){a[0],a[1],b[0],b[1]};
            bfr[ct][s] = cv.s;
        }
    }

    f4v acc[5];
    #pragma unroll
    for (int ct = 0; ct < 5; ct++) acc[ct] = (f4v){0.f,0.f,0.f,0.f};

    int m = rowbase + l16;
    int mc = m < N_NODES ? m : N_NODES - 1;
    #pragma unroll
    for (int s = 0; s < 4; s++){
        int k0 = s*32 + quad*8;
        union { u4v u; s8v s8; } cin;
        cin.u = *(const u4v*)(out1b + (size_t)mc*128 + k0);
        u4v up;
        #pragma unroll
        for (int i = 0; i < 4; i++){
            float f0 = lo16(cin.u[i]), f1 = hi16(cin.u[i]);
            int k = k0 + 2*i;
            up[i] = pack2(f0*scl[k] + shl[k], f1*scl[k+1] + shl[k+1]);
        }
        union { u4v u; s8v s8; } cv; cv.u = up;
        #pragma unroll
        for (int ct = 0; ct < 5; ct++)
            acc[ct] = __builtin_amdgcn_mfma_f32_16x16x32_bf16(cv.s8, bfr[ct][s], acc[ct], 0,0,0);
    }

    #pragma unroll
    for (int ct = 0; ct < 5; ct++){
        int col = ct*16 + l16;
        #pragma unroll
        for (int r = 0; r < 4; r++){
            int row = rowbase + quad*4 + r;
            if (row < N_NODES) h2[(size_t)row*80 + col] = f2bb(acc[ct][r]);
        }
    }

    // fused att2: head0 = cols 0..39, head1 = cols 40..79.
    #pragma unroll
    for (int r = 0; r < 4; r++){
        float vs0 = 0.f, vs1 = 0.f, vd0 = 0.f, vd1 = 0.f;
        #pragma unroll
        for (int ct = 0; ct < 5; ct++){
            int col = ct*16 + l16;
            float ps = acc[ct][r]*asv[ct], pd = acc[ct][r]*adv[ct];
            if (col < 40){ vs0 += ps; vd0 += pd; } else { vs1 += ps; vd1 += pd; }
        }
        #pragma unroll
        for (int o = 1; o < 16; o <<= 1){
            vs0 += __shfl_xor(vs0, o, 64); vs1 += __shfl_xor(vs1, o, 64);
            vd0 += __shfl_xor(vd0, o, 64); vd1 += __shfl_xor(vd1, o, 64);
        }
        if (l16 == 0){
            int row = rowbase + quad*4 + r;
            if (row < N_NODES){
                aS[row*2 + 0] = vs0; aS[row*2 + 1] = vs1;
                aD[row*2 + 0] = vd0; aD[row*2 + 1] = vd1;
            }
        }
    }
}

// ---------------- layer-2 agg: 2 nodes/wave, 10 lanes/edge x dwordx4 --------
// (R3 form — best measured.) Each half-wave owns one node. c=ll%10 owns bytes
// 16c..16c+15 of edge-group g=ll/10 in {0,1,2} (lanes ll>=30 idle). Main loop
// = 9 edges/half-iter (3 gathers in flight); 3-edge tail. Fold = ONE round.
__global__ __launch_bounds__(256) void k_agg2(
    const int* __restrict__ cur, const int* __restrict__ deg,
    const int* __restrict__ eidx, const float* __restrict__ aS,
    const float* __restrict__ aD, const uint32_t* __restrict__ h2u,
    const void* __restrict__ b2v, const int* __restrict__ flag,
    void* __restrict__ out)
{
    __shared__ uint2 lse[4][2][CH2 + 4];   // 16.6 KB
    const int wv = threadIdx.x >> 6;
    const int l = threadIdx.x & 63;
    const int half = l >> 5, ll = l & 31;
    const int d = blockIdx.x*8 + wv*2 + half;   // 12500*8 = 100000 exact
    const int isb = *flag;
    const int c = ll % 10;               // feature slot within edge
    const int g = ll / 10;               // edge group 0..2 (3 = idle lanes)
    const bool act = ll < 30;
    const int gq = act ? g : 0;          // safe lse index for idle lanes
    const uint32_t c16 = (uint32_t)(c*16);
    int end   = cur[d];
    int start = end - deg[d];
    float2 ad = *(const float2*)(aD + d*2);
    const int sh = (c >= 5) ? 16 : 0;    // cols 8c..8c+7: head1 iff 8c >= 40
    float den0 = 0.f, den1 = 0.f;
    float acc[8];
    #pragma unroll
    for (int k = 0; k < 8; k++) acc[k] = 0.f;
    const char* hb = (const char*)h2u;

#define G2(P, W) { u4v Gx = *(const u4v*)(hb + ((P).x + c16)); \
    float Wf = (W); \
    acc[0] += Wf*lo16(Gx[0]); acc[1] += Wf*hi16(Gx[0]); \
    acc[2] += Wf*lo16(Gx[1]); acc[3] += Wf*hi16(Gx[1]); \
    acc[4] += Wf*lo16(Gx[2]); acc[5] += Wf*hi16(Gx[2]); \
    acc[6] += Wf*lo16(Gx[3]); acc[7] += Wf*hi16(Gx[3]); }

    for (int c0 = start; c0 < end; c0 += CH2){
        int c1 = (c0 + CH2 < end) ? c0 + CH2 : end;
        int n = c1 - c0;
        // phase 1: half's 32 lanes parallel over this node's edges
        for (int j = c0 + ll; j < c1; j += 32){
            int s = eidx[j];
            float2 as = *(const float2*)((const char*)aS + ((uint32_t)s*8u));
            float al0 = as.x + ad.x, al1 = as.y + ad.y;
            al0 = al0 > 0.f ? al0 : NEG*al0;
            al1 = al1 > 0.f ? al1 : NEG*al1;
            float e0 = __expf(al0), e1 = __expf(al1);
            lse[wv][half][j - c0] = make_uint2((uint32_t)s * 160u, packh2(e0, e1));
            den0 += e0; den1 += e1;
        }
        int nn = ((n + 2) / 3) * 3;
        if (ll < nn - n) lse[wv][half][n + ll] = make_uint2(0u, 0u);
        // same-wave LDS RAW: in-order per wave, no block barrier needed
        int i = 0;
        for (; i + 9 <= nn; i += 9){     // 3 rounds of 3 edges in flight
            uint2 pa = lse[wv][half][i + gq];
            uint2 pb = lse[wv][half][i + 3 + gq];
            uint2 pc = lse[wv][half][i + 6 + gq];
            G2(pa, act ? hcvt(pa.y, sh) : 0.f);
            G2(pb, act ? hcvt(pb.y, sh) : 0.f);
            G2(pc, act ? hcvt(pc.y, sh) : 0.f);
        }
        for (; i < nn; i += 3){
            uint2 pa = lse[wv][half][i + gq];
            G2(pa, act ? hcvt(pa.y, sh) : 0.f);
        }
    }
#undef G2
    // den reduce within each half (both nodes share the 5 rounds)
    #pragma unroll
    for (int o = 1; o < 32; o <<= 1){
        den0 += __shfl_xor(den0, o, 64);
        den1 += __shfl_xor(den1, o, 64);
    }
    // fold the 3 edge-groups of each half: lanes ll<10 get g0+g1+g2.
    #pragma unroll
    for (int k = 0; k < 8; k++)
        acc[k] += __shfl(acc[k], l + 10, 64) + __shfl(acc[k], l + 20, 64);
    // lanes ll 0..9 hold totals for cols 8*ll..8*ll+7 of node d
    float r = 1.f / fmaxf((c < 5) ? den0 : den1, 1e-20f);
    #pragma unroll
    for (int k = 0; k < 8; k++) acc[k] *= r;

    // head-mean: lane ll<5 (classes 8ll..8ll+7, head0) pairs with ll+5 (head1)
    int lb = (ll < 5) ? ll : 0;
    float v[8];
    float mx = -1e30f;
    #pragma unroll
    for (int k = 0; k < 8; k++){
        float t = __shfl(acc[k], l + 5, 64);
        v[k] = 0.5f*(acc[k] + t) + rdf(b2v, 8*lb + k, isb);
        mx = fmaxf(mx, v[k]);
    }
    if (ll >= 5) mx = -1e30f;
    // log_softmax over 40 classes in lanes ll 0..4 x 8 slots (per half)
    mx = fmaxf(mx, __shfl_xor(mx, 1, 64));
    mx = fmaxf(mx, __shfl_xor(mx, 2, 64));
    mx = fmaxf(mx, __shfl_xor(mx, 4, 64));
    float ex = 0.f;
    if (ll < 5){
        #pragma unroll
        for (int k = 0; k < 8; k++) ex += __expf(v[k] - mx);
    }
    ex += __shfl_xor(ex, 1, 64);
    ex += __shfl_xor(ex, 2, 64);
    ex += __shfl_xor(ex, 4, 64);
    float lsf = __logf(ex);
    if (ll < 5){
        if (isb){
            u4v o;
            #pragma unroll
            for (int q = 0; q < 4; q++)
                o[q] = pack2(v[2*q] - mx - lsf, v[2*q+1] - mx - lsf);
            *(u4v*)((uint32_t*)out + (size_t)d*20 + 4*ll) = o;
        } else {
            float4 o0, o1;
            o0.x = v[0]-mx-lsf; o0.y = v[1]-mx-lsf; o0.z = v[2]-mx-lsf; o0.w = v[3]-mx-lsf;
            o1.x = v[4]-mx-lsf; o1.y = v[5]-mx-lsf; o1.z = v[6]-mx-lsf; o1.w = v[7]-mx-lsf;
            ((float4*)out)[(size_t)d*10 + 2*ll]     = o0;
            ((float4*)out)[(size_t)d*10 + 2*ll + 1] = o1;
        }
    }
}

extern "C" void kernel_launch(void* const* d_in, const int* in_sizes, int n_in,
                              void* d_out, int out_size, void* d_ws, size_t ws_size,
                              hipStream_t stream)
{
    const void* x    = d_in[0];
    const int*  ei   = (const int*)d_in[1];
    const void* W1   = d_in[2];
    const void* as1  = d_in[3];
    const void* ad1  = d_in[4];
    // d_in[5] = b1: cancels exactly through BatchNorm mean subtraction
    const void* gamma = d_in[6];
    const void* beta  = d_in[7];
    const void* W2   = d_in[8];
    const void* as2  = d_in[9];
    const void* ad2  = d_in[10];
    const void* b2v  = d_in[11];
    const int* esrc = ei;
    const int* edst = ei + N_EDGES;

    // --- workspace: ~62 MB total (81.7 MB proven safe) ---
    char* ws = (char*)d_ws;
    size_t off = 0;
    auto alloc = [&](size_t bytes) {
        void* p = ws + off;
        off += (bytes + 255) & ~(size_t)255;
        return p;
    };
    int*   flag  = (int*)alloc(256);
    float* stats = (float*)alloc(sizeof(float)*256);
    float* aS1   = (float*)alloc(sizeof(float)*N_NODES*2);
    float* aD1   = (float*)alloc(sizeof(float)*N_NODES*2);
    float* aS2   = (float*)alloc(sizeof(float)*N_NODES*2);
    float* aD2   = (float*)alloc(sizeof(float)*N_NODES*2);
    int*   deg   = (int*)alloc(sizeof(int)*N_NODES);
    int*   cur   = (int*)alloc(sizeof(int)*N_NODES);
    int*   curw  = (int*)alloc(sizeof(int)*N_NODES);
    int*   bsum  = (int*)alloc(sizeof(int)*NBUCK);
    int*   bsumx = (int*)alloc(sizeof(int)*NBUCK);
    int*   eidx  = (int*)alloc(sizeof(int)*(size_t)ET);                   // 6.8 MB
    unsigned short* h1  = (unsigned short*)alloc(2*(size_t)N_NODES*HID);  // 25.6 MB
    unsigned short* out1 = (unsigned short*)alloc(2*(size_t)N_NODES*HID); // 25.6 MB
    unsigned short* h2  = h1;            // alias: h1 dead after k_agg1

    k_init<<<NBUCK, 256, 0, stream>>>((const uint32_t*)W1, flag, stats, deg);
    k_gemm1<<<3125, 256, 0, stream>>>(x, W1, as1, ad1, flag, h1, aS1, aD1);
    k_hist<<<1700, 256, 0, stream>>>(esrc, edst, deg);
    k_scan1<<<NBUCK, 256, 0, stream>>>(deg, cur, bsum);
    k_scan2<<<1, 512, 0, stream>>>(bsum, bsumx);
    k_scan3<<<NBUCK, 256, 0, stream>>>(deg, bsumx, cur, curw);
    k_scatter<<<1700, 256, 0, stream>>>(esrc, edst, curw, eidx);
    k_agg1<<<12500, 256, 0, stream>>>(cur, deg, eidx, aS1, aD1,
                                      (const uint32_t*)h1, (uint32_t*)out1);
    k_bnstats<<<128, 256, 0, stream>>>((const uint32_t*)out1, stats);
    k_gemm2<<<1563, 256, 0, stream>>>(out1, stats, gamma, beta, W2, as2, ad2,
                                      flag, h2, aS2, aD2);
    k_agg2<<<12500, 256, 0, stream>>>(cur, deg, eidx, aS2, aD2,
                                      (const uint32_t*)h2, b2v, flag, d_out);
}

// Round 11
// 390.940 us; speedup vs baseline: 1.4494x; 1.4494x over previous
//
#include <hip/hip_runtime.h>
#include <hip/hip_bf16.h>
#include <hip/hip_fp16.h>
#include <stdint.h>

#define N_NODES 100000
#define N_EDGES 1600000
#define ET (N_EDGES + N_NODES)   // edges + self-loops
#define HID 128
#define C2 40
#define F2 80
#define NEG 0.2f
#define BN_EPS 1e-5f
#define NBUCK 391                // ceil(100000/256) coarse buckets (256 nodes each)
#define BCAP 6144                // slots per bucket (mean 4608, sd 66 -> +23 sigma)
#define NBB 640                  // bin-pass blocks
#define EPB ((ET + NBB - 1) / NBB)
#define CH2 256                  // per-NODE LDS edge cache (max deg ~45 << 256)

typedef __hip_bfloat16 bf16;
typedef __attribute__((ext_vector_type(8))) short s8v;          // 8 bf16 MFMA A/B frag
typedef __attribute__((ext_vector_type(4))) float f4v;          // MFMA C/D frag
typedef __attribute__((ext_vector_type(4))) unsigned int u4v;
typedef __attribute__((ext_vector_type(2))) unsigned int u2v;

__device__ __forceinline__ float b2f(bf16 v){ return __bfloat162float(v); }
__device__ __forceinline__ float rdf(const void* p, size_t i, int isb){
    return isb ? b2f(((const bf16*)p)[i]) : ((const float*)p)[i];
}
__device__ __forceinline__ unsigned short f2bb(float v){
    bf16 h = __float2bfloat16(v);
    return *(unsigned short*)&h;
}
__device__ __forceinline__ uint32_t pack2(float a, float b){
    return (uint32_t)f2bb(a) | ((uint32_t)f2bb(b) << 16);
}
__device__ __forceinline__ uint32_t packh2(float a, float b){
    return (uint32_t)__half_as_ushort(__float2half(a))
         | ((uint32_t)__half_as_ushort(__float2half(b)) << 16);
}
__device__ __forceinline__ float lo16(uint32_t u){ return __uint_as_float(u << 16); }
__device__ __forceinline__ float hi16(uint32_t u){ return __uint_as_float(u & 0xFFFF0000u); }
__device__ __forceinline__ float hcvt(uint32_t w, int sh){
    return __half2float(__ushort_as_half((unsigned short)((w >> sh) & 0xFFFFu)));
}

// ---------------- init: dtype flag + zero gcur/stats ------------------------
__global__ __launch_bounds__(256) void k_init(
    const uint32_t* __restrict__ w1bits, int* __restrict__ flag,
    int* __restrict__ gcur, float* __restrict__ stats)
{
    __shared__ int cnt;
    int t = threadIdx.x;
    if (t == 0) cnt = 0;
    __syncthreads();
    uint32_t b = w1bits[t];
    float lo = __uint_as_float((b & 0xFFFFu) << 16);
    float a = fabsf(lo);
    if (a > 1e-8f && a < 1.0f) atomicAdd(&cnt, 1);
    for (int i = t; i < NBUCK; i += 256) gcur[i] = 0;
    stats[t] = 0.f;
    __syncthreads();
    if (t == 0) *flag = (cnt >= 192) ? 1 : 0;
}

// ---------------- GEMM1 (MFMA): h1 = x @ W1, + fused att1 dots --------------
__global__ __launch_bounds__(256) void k_gemm1(
    const void* __restrict__ x, const void* __restrict__ W1,
    const void* __restrict__ attS, const void* __restrict__ attD,
    const int* __restrict__ flag, unsigned short* __restrict__ h1,
    float* __restrict__ aS, float* __restrict__ aD)
{
    __shared__ __attribute__((aligned(16))) unsigned short wT[128*132]; // 33.8 KB
    const int isb = *flag;
    const int tid = threadIdx.x;
    if (isb) {
        const unsigned short* w = (const unsigned short*)W1;
        for (int idx = tid; idx < 128*128; idx += 256){
            int k = idx >> 7, n = idx & 127;
            wT[n*132 + k] = w[idx];
        }
    } else {
        const float* w = (const float*)W1;
        for (int idx = tid; idx < 128*128; idx += 256){
            int k = idx >> 7, n = idx & 127;
            wT[n*132 + k] = f2bb(w[idx]);
        }
    }
    __syncthreads();

    const int w4 = tid >> 6, lane = tid & 63, quad = lane >> 4, l16 = lane & 15;
    const int rowbase = blockIdx.x*32 + (w4 >> 1)*16;   // 3125*32 = 100000 exact
    const int colbase = (w4 & 1)*64;
    const int head = w4 & 1;

    s8v bfr[4][4];
    float asv[4], adv[4];
    #pragma unroll
    for (int ct = 0; ct < 4; ct++){
        int n = colbase + ct*16 + l16;
        asv[ct] = rdf(attS, n, isb);
        adv[ct] = rdf(attD, n, isb);
        #pragma unroll
        for (int s = 0; s < 4; s++){
            int k0 = s*32 + quad*8;
            const unsigned short* p = &wT[n*132 + k0];
            u2v a = *(const u2v*)p, b = *(const u2v*)(p+4);
            union { u4v u; s8v s; } cv; cv.u = (u4v){a[0],a[1],b[0],b[1]};
            bfr[ct][s] = cv.s;
        }
    }

    f4v acc[4];
    #pragma unroll
    for (int ct = 0; ct < 4; ct++) acc[ct] = (f4v){0.f,0.f,0.f,0.f};

    const int m = rowbase + l16;
    #pragma unroll
    for (int s = 0; s < 4; s++){
        int k0 = s*32 + quad*8;
        s8v af;
        if (isb){
            union { u4v u; s8v s; } cv;
            cv.u = *(const u4v*)((const unsigned short*)x + (size_t)m*128 + k0);
            af = cv.s;
        } else {
            const float* xp = (const float*)x + (size_t)m*128 + k0;
            f4v f0 = *(const f4v*)xp, f1 = *(const f4v*)(xp+4);
            union { u4v u; s8v s; } cv;
            cv.u = (u4v){pack2(f0[0],f0[1]), pack2(f0[2],f0[3]),
                         pack2(f1[0],f1[1]), pack2(f1[2],f1[3])};
            af = cv.s;
        }
        #pragma unroll
        for (int ct = 0; ct < 4; ct++)
            acc[ct] = __builtin_amdgcn_mfma_f32_16x16x32_bf16(af, bfr[ct][s], acc[ct], 0,0,0);
    }

    // C/D: col = lane&15, row = quad*4 + reg
    #pragma unroll
    for (int ct = 0; ct < 4; ct++){
        int col = colbase + ct*16 + l16;
        #pragma unroll
        for (int r = 0; r < 4; r++){
            int row = rowbase + quad*4 + r;
            h1[(size_t)row*128 + col] = f2bb(acc[ct][r]);
        }
    }

    // fused att1: per row, reduce acc*att over wave's 64 cols (one head).
    #pragma unroll
    for (int r = 0; r < 4; r++){
        float vs = 0.f, vd = 0.f;
        #pragma unroll
        for (int ct = 0; ct < 4; ct++){ vs += acc[ct][r]*asv[ct]; vd += acc[ct][r]*adv[ct]; }
        #pragma unroll
        for (int o = 1; o < 16; o <<= 1){
            vs += __shfl_xor(vs, o, 64);
            vd += __shfl_xor(vd, o, 64);
        }
        if (l16 == 0){
            int row = rowbase + quad*4 + r;
            aS[row*2 + head] = vs;
            aD[row*2 + head] = vd;
        }
    }
}

// ---------------- CSR pass 1: LDS-binned coarse scatter ---------------------
__global__ __launch_bounds__(256) void k_bin(
    const int* __restrict__ esrc, const int* __restrict__ edst,
    int* __restrict__ gcur, uint32_t* __restrict__ staging)
{
    __shared__ int cnt[NBUCK];
    __shared__ int bb[NBUCK];
    const int t = threadIdx.x;
    for (int i = t; i < NBUCK; i += 256) cnt[i] = 0;
    __syncthreads();
    const int e0 = blockIdx.x * EPB;
    const int e1 = (e0 + EPB < ET) ? e0 + EPB : ET;
    for (int e = e0 + t; e < e1; e += 256){
        int d = (e < N_EDGES) ? edst[e] : e - N_EDGES;
        atomicAdd(&cnt[d >> 8], 1);
    }
    __syncthreads();
    // rotate flush order by block to avoid lockstep per-address atomic chains
    const int bofs = (int)(blockIdx.x % NBUCK);
    for (int i = t; i < NBUCK; i += 256){
        int bkt = i + bofs; if (bkt >= NBUCK) bkt -= NBUCK;
        int c = cnt[bkt];
        bb[bkt] = c ? atomicAdd(&gcur[bkt], c) : 0;
        cnt[bkt] = 0;
    }
    __syncthreads();
    for (int e = e0 + t; e < e1; e += 256){
        int d, s;
        if (e < N_EDGES){ s = esrc[e]; d = edst[e]; } else { s = d = e - N_EDGES; }
        int b = d >> 8;
        int r = atomicAdd(&cnt[b], 1);
        int p = bb[b] + r;
        if (p < BCAP) staging[(size_t)b*BCAP + p] = ((uint32_t)s << 8) | (uint32_t)(d & 255);
    }
}

// ---------------- CSR pass 2: per-bucket fine counting sort -----------------
__global__ __launch_bounds__(256) void k_sort(
    const int* __restrict__ gcur, const uint32_t* __restrict__ staging,
    int* __restrict__ deg, int* __restrict__ cur, int* __restrict__ eidx)
{
    __shared__ int h[256], sc[256], rk[256];
    __shared__ int lsrc[BCAP];
    const int b = blockIdx.x;
    const int t = threadIdx.x;
    const int base = b * BCAP;
    int cnt = gcur[b];
    if (cnt > BCAP) cnt = BCAP;
    h[t] = 0; rk[t] = 0;
    __syncthreads();
    for (int i = t; i < cnt; i += 256)
        atomicAdd(&h[staging[base + i] & 255u], 1);
    __syncthreads();
    sc[t] = h[t];
    __syncthreads();
    for (int off = 1; off < 256; off <<= 1){
        int v = (t >= off) ? sc[t - off] : 0;
        __syncthreads();
        sc[t] += v;
        __syncthreads();
    }
    int dg = b*256 + t;
    if (dg < N_NODES){
        deg[dg] = h[t];
        cur[dg] = base + sc[t];    // end pointer; start = end - deg
    }
    __syncthreads();
    for (int i = t; i < cnt; i += 256){
        uint32_t w = staging[base + i];
        int dl = w & 255u;
        int r = atomicAdd(&rk[dl], 1);
        lsrc[sc[dl] - h[dl] + r] = (int)(w >> 8);
    }
    __syncthreads();
    for (int i = t; i < cnt; i += 256) eidx[base + i] = lsrc[i];
}

// ---------------- layer-1 agg: 2 nodes/wave, 16 lanes/edge x dwordx4 --------
// (Best measured: 67 us, FETCH ~210 MB = 8 XCDs x table — the structural
// floor for this access pattern.) Each half-wave (32 lanes) owns one node.
// c=ll&15 owns bytes 16c..16c+15 of edge-group g=ll>>4; 8 edges/iter with 4
// dwordx4 in flight. Phase 1 caches exp-weights in LDS with 32-lane
// parallelism; den reduce shared by both nodes; fold = ONE xor(16).
__global__ __launch_bounds__(256) void k_agg1(
    const int* __restrict__ cur, const int* __restrict__ deg,
    const int* __restrict__ eidx, const float* __restrict__ aS,
    const float* __restrict__ aD, const uint32_t* __restrict__ h1u,
    uint32_t* __restrict__ out1u)
{
    __shared__ uint2 lse[4][2][CH2 + 4];   // 16.6 KB
    const int wv = threadIdx.x >> 6;
    const int l = threadIdx.x & 63;
    const int half = l >> 5, ll = l & 31;
    const int d = blockIdx.x*8 + wv*2 + half;   // 12500*8 = 100000 exact
    const int c = ll & 15;               // feature slot within edge
    const int g = ll >> 4;               // edge group 0..1
    const uint32_t c16 = (uint32_t)(c*16);
    int end   = cur[d];
    int start = end - deg[d];
    float2 ad = *(const float2*)(aD + d*2);
    const int sh = (c >= 8) ? 16 : 0;    // cols 8c..8c+7: head1 iff 8c >= 64
    float den0 = 0.f, den1 = 0.f;
    float acc[8];
    #pragma unroll
    for (int k = 0; k < 8; k++) acc[k] = 0.f;
    const char* hb = (const char*)h1u;

#define G1(P, W) { u4v Gx = *(const u4v*)(hb + ((P).x + c16)); \
    float Wf = (W); \
    acc[0] += Wf*lo16(Gx[0]); acc[1] += Wf*hi16(Gx[0]); \
    acc[2] += Wf*lo16(Gx[1]); acc[3] += Wf*hi16(Gx[1]); \
    acc[4] += Wf*lo16(Gx[2]); acc[5] += Wf*hi16(Gx[2]); \
    acc[6] += Wf*lo16(Gx[3]); acc[7] += Wf*hi16(Gx[3]); }

    for (int c0 = start; c0 < end; c0 += CH2){
        int c1 = (c0 + CH2 < end) ? c0 + CH2 : end;
        int n = c1 - c0;
        // phase 1: half's 32 lanes parallel over this node's edges
        for (int j = c0 + ll; j < c1; j += 32){
            int s = eidx[j];
            float2 as = *(const float2*)((const char*)aS + ((uint32_t)s*8u));
            float al0 = as.x + ad.x, al1 = as.y + ad.y;
            al0 = al0 > 0.f ? al0 : NEG*al0;
            al1 = al1 > 0.f ? al1 : NEG*al1;
            float e0 = __expf(al0), e1 = __expf(al1);
            lse[wv][half][j - c0] = make_uint2((uint32_t)s << 8, packh2(e0, e1));
            den0 += e0; den1 += e1;
        }
        int nn = (n + 1) & ~1;
        if (ll < nn - n) lse[wv][half][n + ll] = make_uint2(0u, 0u);
        // same-wave LDS RAW: in-order per wave, no block barrier needed
        int i = 0;
        for (; i + 8 <= nn; i += 8){     // 4 rounds of 2 edges in flight
            uint2 pa = lse[wv][half][i + g];
            uint2 pb = lse[wv][half][i + 2 + g];
            uint2 pc = lse[wv][half][i + 4 + g];
            uint2 pd = lse[wv][half][i + 6 + g];
            G1(pa, hcvt(pa.y, sh));
            G1(pb, hcvt(pb.y, sh));
            G1(pc, hcvt(pc.y, sh));
            G1(pd, hcvt(pd.y, sh));
        }
        for (; i < nn; i += 2){
            uint2 pa = lse[wv][half][i + g];
            G1(pa, hcvt(pa.y, sh));
        }
    }
#undef G1
    // den reduce within each half (both nodes share the 5 rounds)
    #pragma unroll
    for (int o = 1; o < 32; o <<= 1){
        den0 += __shfl_xor(den0, o, 64);
        den1 += __shfl_xor(den1, o, 64);
    }
    // fold the 2 edge-groups of each half
    #pragma unroll
    for (int k = 0; k < 8; k++)
        acc[k] += __shfl_xor(acc[k], 16, 64);
    float r = 1.f / fmaxf((c < 8) ? den0 : den1, 1e-20f);
    if (ll < 16){
        u4v o;
        #pragma unroll
        for (int q = 0; q < 4; q++) o[q] = pack2(acc[2*q]*r, acc[2*q+1]*r);
        *(u4v*)(out1u + (size_t)d*64 + 4*c) = o;
    }
}

// ---------------- BatchNorm stats: per-block LDS reduce, then 1 atomic ------
__global__ __launch_bounds__(256) void k_bnstats(
    const uint32_t* __restrict__ out1u, float* __restrict__ stats)
{
    __shared__ float red[4][64][4];      // wave x feat-pair x {s0,s1,q0,q1} = 4 KB
    int fp = threadIdx.x & 63;
    int wv = threadIdx.x >> 6;
    float s0 = 0.f, q0 = 0.f, s1 = 0.f, q1 = 0.f;
    for (int r = blockIdx.x*4 + wv; r < N_NODES; r += 1000){   // 250 blocks
        uint32_t u = out1u[(size_t)r*64 + fp];
        float f0 = lo16(u), f1 = hi16(u);
        s0 += f0; q0 += f0*f0; s1 += f1; q1 += f1*f1;
    }
    red[wv][fp][0] = s0; red[wv][fp][1] = s1;
    red[wv][fp][2] = q0; red[wv][fp][3] = q1;
    __syncthreads();
    if (threadIdx.x < 64){
        int l = threadIdx.x;
        float a0=0.f, a1=0.f, b0=0.f, b1=0.f;
        #pragma unroll
        for (int w = 0; w < 4; w++){
            a0 += red[w][l][0]; a1 += red[w][l][1];
            b0 += red[w][l][2]; b1 += red[w][l][3];
        }
        unsafeAtomicAdd(&stats[2*l],       a0);
        unsafeAtomicAdd(&stats[2*l+1],     a1);
        unsafeAtomicAdd(&stats[128+2*l],   b0);
        unsafeAtomicAdd(&stats[128+2*l+1], b1);
    }
}

// ---------------- GEMM2 (MFMA): h2 = BN(out1) @ W2, + fused att2, BN-fin ----
__global__ __launch_bounds__(256) void k_gemm2(
    const unsigned short* __restrict__ out1b, const float* __restrict__ stats,
    const void* __restrict__ gamma, const void* __restrict__ beta,
    const void* __restrict__ W2, const void* __restrict__ attS,
    const void* __restrict__ attD, const int* __restrict__ flag,
    unsigned short* __restrict__ h2, float* __restrict__ aS, float* __restrict__ aD)
{
    __shared__ __attribute__((aligned(16))) unsigned short wT[80*132]; // 21.1 KB
    __shared__ float scl[128], shl[128];
    const int isb = *flag;
    const int tid = threadIdx.x;
    for (int idx = tid; idx < 128*80; idx += 256){
        int k = idx / 80, n = idx - k*80;
        wT[n*132 + k] = isb ? ((const unsigned short*)W2)[idx]
                            : f2bb(((const float*)W2)[idx]);
    }
    if (tid < 128){   // inline BN finalize
        float mean = stats[tid] * (1.f / N_NODES);
        float var = fmaxf(stats[128+tid] * (1.f / N_NODES) - mean*mean, 0.f);
        float rs = rsqrtf(var + BN_EPS);
        float sc = rdf(gamma, tid, isb) * rs;
        scl[tid] = sc;
        shl[tid] = rdf(beta, tid, isb) - mean*sc;
    }
    __syncthreads();

    const int w4 = tid >> 6, lane = tid & 63, quad = lane >> 4, l16 = lane & 15;
    const int rowbase = blockIdx.x*64 + w4*16;

    s8v bfr[5][4];
    float asv[5], adv[5];
    #pragma unroll
    for (int ct = 0; ct < 5; ct++){
        int n = ct*16 + l16;
        asv[ct] = rdf(attS, n, isb);
        adv[ct] = rdf(attD, n, isb);
        #pragma unroll
        for (int s = 0; s < 4; s++){
            int k0 = s*32 + quad*8;
            const unsigned short* p = &wT[n*132 + k0];
            u2v a = *(const u2v*)p, b = *(const u2v*)(p+4);
            union { u4v u; s8v s; } cv; cv.u = (u4v){a[0],a[1],b[0],b[1]};
            bfr[ct][s] = cv.s;
        }
    }

    f4v acc[5];
    #pragma unroll
    for (int ct = 0; ct < 5; ct++) acc[ct] = (f4v){0.f,0.f,0.f,0.f};

    int m = rowbase + l16;
    int mc = m < N_NODES ? m : N_NODES - 1;
    #pragma unroll
    for (int s = 0; s < 4; s++){
        int k0 = s*32 + quad*8;
        union { u4v u; s8v s8; } cin;
        cin.u = *(const u4v*)(out1b + (size_t)mc*128 + k0);
        u4v up;
        #pragma unroll
        for (int i = 0; i < 4; i++){
            float f0 = lo16(cin.u[i]), f1 = hi16(cin.u[i]);
            int k = k0 + 2*i;
            up[i] = pack2(f0*scl[k] + shl[k], f1*scl[k+1] + shl[k+1]);
        }
        union { u4v u; s8v s8; } cv; cv.u = up;
        #pragma unroll
        for (int ct = 0; ct < 5; ct++)
            acc[ct] = __builtin_amdgcn_mfma_f32_16x16x32_bf16(cv.s8, bfr[ct][s], acc[ct], 0,0,0);
    }

    #pragma unroll
    for (int ct = 0; ct < 5; ct++){
        int col = ct*16 + l16;
        #pragma unroll
        for (int r = 0; r < 4; r++){
            int row = rowbase + quad*4 + r;
            if (row < N_NODES) h2[(size_t)row*80 + col] = f2bb(acc[ct][r]);
        }
    }

    // fused att2: head0 = cols 0..39, head1 = cols 40..79.
    #pragma unroll
    for (int r = 0; r < 4; r++){
        float vs0 = 0.f, vs1 = 0.f, vd0 = 0.f, vd1 = 0.f;
        #pragma unroll
        for (int ct = 0; ct < 5; ct++){
            int col = ct*16 + l16;
            float ps = acc[ct][r]*asv[ct], pd = acc[ct][r]*adv[ct];
            if (col < 40){ vs0 += ps; vd0 += pd; } else { vs1 += ps; vd1 += pd; }
        }
        #pragma unroll
        for (int o = 1; o < 16; o <<= 1){
            vs0 += __shfl_xor(vs0, o, 64); vs1 += __shfl_xor(vs1, o, 64);
            vd0 += __shfl_xor(vd0, o, 64); vd1 += __shfl_xor(vd1, o, 64);
        }
        if (l16 == 0){
            int row = rowbase + quad*4 + r;
            if (row < N_NODES){
                aS[row*2 + 0] = vs0; aS[row*2 + 1] = vs1;
                aD[row*2 + 0] = vd0; aD[row*2 + 1] = vd1;
            }
        }
    }
}

// ---------------- layer-2 agg: 2 nodes/wave, 10 lanes/edge x dwordx4 --------
// (Best measured form.) Each half-wave owns one node. c=ll%10 owns bytes
// 16c..16c+15 of edge-group g=ll/10 in {0,1,2} (lanes ll>=30 idle). Main loop
// = 9 edges/half-iter (3 gathers in flight); 3-edge tail. Fold = ONE round.
__global__ __launch_bounds__(256) void k_agg2(
    const int* __restrict__ cur, const int* __restrict__ deg,
    const int* __restrict__ eidx, const float* __restrict__ aS,
    const float* __restrict__ aD, const uint32_t* __restrict__ h2u,
    const void* __restrict__ b2v, const int* __restrict__ flag,
    void* __restrict__ out)
{
    __shared__ uint2 lse[4][2][CH2 + 4];   // 16.6 KB
    const int wv = threadIdx.x >> 6;
    const int l = threadIdx.x & 63;
    const int half = l >> 5, ll = l & 31;
    const int d = blockIdx.x*8 + wv*2 + half;   // 12500*8 = 100000 exact
    const int isb = *flag;
    const int c = ll % 10;               // feature slot within edge
    const int g = ll / 10;               // edge group 0..2 (3 = idle lanes)
    const bool act = ll < 30;
    const int gq = act ? g : 0;          // safe lse index for idle lanes
    const uint32_t c16 = (uint32_t)(c*16);
    int end   = cur[d];
    int start = end - deg[d];
    float2 ad = *(const float2*)(aD + d*2);
    const int sh = (c >= 5) ? 16 : 0;    // cols 8c..8c+7: head1 iff 8c >= 40
    float den0 = 0.f, den1 = 0.f;
    float acc[8];
    #pragma unroll
    for (int k = 0; k < 8; k++) acc[k] = 0.f;
    const char* hb = (const char*)h2u;

#define G2(P, W) { u4v Gx = *(const u4v*)(hb + ((P).x + c16)); \
    float Wf = (W); \
    acc[0] += Wf*lo16(Gx[0]); acc[1] += Wf*hi16(Gx[0]); \
    acc[2] += Wf*lo16(Gx[1]); acc[3] += Wf*hi16(Gx[1]); \
    acc[4] += Wf*lo16(Gx[2]); acc[5] += Wf*hi16(Gx[2]); \
    acc[6] += Wf*lo16(Gx[3]); acc[7] += Wf*hi16(Gx[3]); }

    for (int c0 = start; c0 < end; c0 += CH2){
        int c1 = (c0 + CH2 < end) ? c0 + CH2 : end;
        int n = c1 - c0;
        // phase 1: half's 32 lanes parallel over this node's edges
        for (int j = c0 + ll; j < c1; j += 32){
            int s = eidx[j];
            float2 as = *(const float2*)((const char*)aS + ((uint32_t)s*8u));
            float al0 = as.x + ad.x, al1 = as.y + ad.y;
            al0 = al0 > 0.f ? al0 : NEG*al0;
            al1 = al1 > 0.f ? al1 : NEG*al1;
            float e0 = __expf(al0), e1 = __expf(al1);
            lse[wv][half][j - c0] = make_uint2((uint32_t)s * 160u, packh2(e0, e1));
            den0 += e0; den1 += e1;
        }
        int nn = ((n + 2) / 3) * 3;
        if (ll < nn - n) lse[wv][half][n + ll] = make_uint2(0u, 0u);
        // same-wave LDS RAW: in-order per wave, no block barrier needed
        int i = 0;
        for (; i + 9 <= nn; i += 9){     // 3 rounds of 3 edges in flight
            uint2 pa = lse[wv][half][i + gq];
            uint2 pb = lse[wv][half][i + 3 + gq];
            uint2 pc = lse[wv][half][i + 6 + gq];
            G2(pa, act ? hcvt(pa.y, sh) : 0.f);
            G2(pb, act ? hcvt(pb.y, sh) : 0.f);
            G2(pc, act ? hcvt(pc.y, sh) : 0.f);
        }
        for (; i < nn; i += 3){
            uint2 pa = lse[wv][half][i + gq];
            G2(pa, act ? hcvt(pa.y, sh) : 0.f);
        }
    }
#undef G2
    // den reduce within each half (both nodes share the 5 rounds)
    #pragma unroll
    for (int o = 1; o < 32; o <<= 1){
        den0 += __shfl_xor(den0, o, 64);
        den1 += __shfl_xor(den1, o, 64);
    }
    // fold the 3 edge-groups of each half: lanes ll<10 get g0+g1+g2.
    #pragma unroll
    for (int k = 0; k < 8; k++)
        acc[k] += __shfl(acc[k], l + 10, 64) + __shfl(acc[k], l + 20, 64);
    // lanes ll 0..9 hold totals for cols 8*ll..8*ll+7 of node d
    float r = 1.f / fmaxf((c < 5) ? den0 : den1, 1e-20f);
    #pragma unroll
    for (int k = 0; k < 8; k++) acc[k] *= r;

    // head-mean: lane ll<5 (classes 8ll..8ll+7, head0) pairs with ll+5 (head1)
    int lb = (ll < 5) ? ll : 0;
    float v[8];
    float mx = -1e30f;
    #pragma unroll
    for (int k = 0; k < 8; k++){
        float t = __shfl(acc[k], l + 5, 64);
        v[k] = 0.5f*(acc[k] + t) + rdf(b2v, 8*lb + k, isb);
        mx = fmaxf(mx, v[k]);
    }
    if (ll >= 5) mx = -1e30f;
    // log_softmax over 40 classes in lanes ll 0..4 x 8 slots (per half)
    mx = fmaxf(mx, __shfl_xor(mx, 1, 64));
    mx = fmaxf(mx, __shfl_xor(mx, 2, 64));
    mx = fmaxf(mx, __shfl_xor(mx, 4, 64));
    float ex = 0.f;
    if (ll < 5){
        #pragma unroll
        for (int k = 0; k < 8; k++) ex += __expf(v[k] - mx);
    }
    ex += __shfl_xor(ex, 1, 64);
    ex += __shfl_xor(ex, 2, 64);
    ex += __shfl_xor(ex, 4, 64);
    float lsf = __logf(ex);
    if (ll < 5){
        if (isb){
            u4v o;
            #pragma unroll
            for (int q = 0; q < 4; q++)
                o[q] = pack2(v[2*q] - mx - lsf, v[2*q+1] - mx - lsf);
            *(u4v*)((uint32_t*)out + (size_t)d*20 + 4*ll) = o;
        } else {
            float4 o0, o1;
            o0.x = v[0]-mx-lsf; o0.y = v[1]-mx-lsf; o0.z = v[2]-mx-lsf; o0.w = v[3]-mx-lsf;
            o1.x = v[4]-mx-lsf; o1.y = v[5]-mx-lsf; o1.z = v[6]-mx-lsf; o1.w = v[7]-mx-lsf;
            ((float4*)out)[(size_t)d*10 + 2*ll]     = o0;
            ((float4*)out)[(size_t)d*10 + 2*ll + 1] = o1;
        }
    }
}

extern "C" void kernel_launch(void* const* d_in, const int* in_sizes, int n_in,
                              void* d_out, int out_size, void* d_ws, size_t ws_size,
                              hipStream_t stream)
{
    const void* x    = d_in[0];
    const int*  ei   = (const int*)d_in[1];
    const void* W1   = d_in[2];
    const void* as1  = d_in[3];
    const void* ad1  = d_in[4];
    // d_in[5] = b1: cancels exactly through BatchNorm mean subtraction
    const void* gamma = d_in[6];
    const void* beta  = d_in[7];
    const void* W2   = d_in[8];
    const void* as2  = d_in[9];
    const void* ad2  = d_in[10];
    const void* b2v  = d_in[11];
    const int* esrc = ei;
    const int* edst = ei + N_EDGES;

    // --- workspace: ~75 MB total (81.7 MB proven safe) ---
    char* ws = (char*)d_ws;
    size_t off = 0;
    auto alloc = [&](size_t bytes) {
        void* p = ws + off;
        off += (bytes + 255) & ~(size_t)255;
        return p;
    };
    int*   flag  = (int*)alloc(256);
    float* stats = (float*)alloc(sizeof(float)*256);
    int*   gcur  = (int*)alloc(sizeof(int)*NBUCK);
    float* aS1   = (float*)alloc(sizeof(float)*N_NODES*2);
    float* aD1   = (float*)alloc(sizeof(float)*N_NODES*2);
    float* aS2   = (float*)alloc(sizeof(float)*N_NODES*2);
    float* aD2   = (float*)alloc(sizeof(float)*N_NODES*2);
    int*   deg   = (int*)alloc(sizeof(int)*N_NODES);
    int*   cur   = (int*)alloc(sizeof(int)*N_NODES);
    uint32_t* staging = (uint32_t*)alloc(sizeof(uint32_t)*(size_t)NBUCK*BCAP); // 9.6 MB
    int*   eidx  = (int*)alloc(sizeof(int)*(size_t)NBUCK*BCAP);                // 9.6 MB
    unsigned short* h1  = (unsigned short*)alloc(2*(size_t)N_NODES*HID);  // 25.6 MB
    unsigned short* out1 = (unsigned short*)alloc(2*(size_t)N_NODES*HID); // 25.6 MB
    unsigned short* h2  = h1;            // alias: h1 dead after k_agg1

    k_init<<<1, 256, 0, stream>>>((const uint32_t*)W1, flag, gcur, stats);
    k_gemm1<<<3125, 256, 0, stream>>>(x, W1, as1, ad1, flag, h1, aS1, aD1);
    k_bin<<<NBB, 256, 0, stream>>>(esrc, edst, gcur, staging);
    k_sort<<<NBUCK, 256, 0, stream>>>(gcur, staging, deg, cur, eidx);
    k_agg1<<<12500, 256, 0, stream>>>(cur, deg, eidx, aS1, aD1,
                                      (const uint32_t*)h1, (uint32_t*)out1);
    k_bnstats<<<250, 256, 0, stream>>>((const uint32_t*)out1, stats);
    k_gemm2<<<1563, 256, 0, stream>>>(out1, stats, gamma, beta, W2, as2, ad2,
                                      flag, h2, aS2, aD2);
    k_agg2<<<12500, 256, 0, stream>>>(cur, deg, eidx, aS2, aD2,
                                      (const uint32_t*)h2, b2v, flag, d_out);
}